// Round 2
// baseline (349.281 us; speedup 1.0000x reference)
//
#include <hip/hip_runtime.h>

#define DEVI __device__ __forceinline__

typedef __attribute__((ext_vector_type(4))) float f32x4;
typedef __attribute__((ext_vector_type(8))) short bf16x8;

DEVI unsigned short f2bf(float f) {
  unsigned int u = __builtin_bit_cast(unsigned int, f);
  u += 0x7FFFu + ((u >> 16) & 1u);   // round-to-nearest-even
  return (unsigned short)(u >> 16);
}

DEVI void load_lds16(const void* g, void* l) {
  __builtin_amdgcn_global_load_lds(
      (__attribute__((address_space(1))) void*)g,
      (__attribute__((address_space(3))) void*)l,
      16, 0, 0);
}

// ---------------- fused fp32 -> bf16 bulk convert (6 segments, 1 launch) ----------------
struct CvtArgs {
  const float* src[6];
  unsigned short* dst[6];
  int cum[6];   // cumulative float4 start offsets
};

__global__ __launch_bounds__(256) void cvt_all(CvtArgs a, int total4) {
  int i = blockIdx.x * 256 + threadIdx.x;
  if (i >= total4) return;
  int s = 0;
#pragma unroll
  for (int k = 1; k < 6; ++k) s += (i >= a.cum[k]);
  const int j = i - a.cum[s];
  const float4 v = reinterpret_cast<const float4*>(a.src[s])[j];
  ushort4 o;
  o.x = f2bf(v.x); o.y = f2bf(v.y); o.z = f2bf(v.z); o.w = f2bf(v.w);
  reinterpret_cast<ushort4*>(a.dst[s])[j] = o;
}

// ---------------- shared 128x128xK=1024 GEMM core: C = A @ W^T + bias, strided epilogue --------
// A: [M,1024] bf16 row-major; W: [1024,1024] bf16 row-major.
// out (m,n): b=m>>log2R, t=m&mask, h=n>>6, d=n&63 -> off=b*sb+t*st+h*sh+d*sd
template<bool OUT_BF16>
DEVI void gemm_core(const unsigned short* __restrict__ A,
                    const unsigned short* __restrict__ W,
                    const float* __restrict__ bias,
                    void* __restrict__ out,
                    float scale, int log2R,
                    long sb, long st, long sh, long sd,
                    int bx, int by)
{
  constexpr int K = 1024;
  __shared__ unsigned short As[128 * 64];
  __shared__ unsigned short Bs[128 * 64];
  const int tid  = threadIdx.x;
  const int wid  = tid >> 6;
  const int lane = tid & 63;
  const int m0 = bx * 128;
  const int n0 = by * 128;
  const int wr = (wid >> 1) * 64;
  const int wc = (wid & 1) * 64;
  const int lg = lane >> 4;
  const int ll = lane & 15;

  f32x4 acc[4][4] = {};

  const char* Ab = (const char*)A + (long)m0 * K * 2;
  const char* Wb = (const char*)W + (long)n0 * K * 2;
  char* AsB = (char*)&As[0];
  char* BsB = (char*)&Bs[0];
  const long rowstride = (long)K * 2;

  for (int kt = 0; kt < K; kt += 64) {
#pragma unroll
    for (int j = 0; j < 4; ++j) {
      const int o    = (wid * 4 + j) * 1024 + lane * 16;
      const int row  = o >> 7;
      const int colb = o & 127;
      load_lds16(Ab + (long)row * rowstride + (long)kt * 2 + colb, AsB + (wid * 4 + j) * 1024);
      load_lds16(Wb + (long)row * rowstride + (long)kt * 2 + colb, BsB + (wid * 4 + j) * 1024);
    }
    __syncthreads();
#pragma unroll
    for (int ks = 0; ks < 2; ++ks) {
      bf16x8 af[4], bfr[4];
#pragma unroll
      for (int i = 0; i < 4; ++i) {
        af[i]  = *(const bf16x8*)&As[(wr + i * 16 + ll) * 64 + ks * 32 + lg * 8];
        bfr[i] = *(const bf16x8*)&Bs[(wc + i * 16 + ll) * 64 + ks * 32 + lg * 8];
      }
#pragma unroll
      for (int i = 0; i < 4; ++i)
#pragma unroll
        for (int j = 0; j < 4; ++j)
          acc[i][j] = __builtin_amdgcn_mfma_f32_16x16x32_bf16(af[i], bfr[j], acc[i][j], 0, 0, 0);
    }
    __syncthreads();
  }

  const int Rmask = (1 << log2R) - 1;
#pragma unroll
  for (int j = 0; j < 4; ++j) {
    const int n = n0 + wc + j * 16 + ll;
    const float bj = bias[n];
    const int h = n >> 6, d = n & 63;
#pragma unroll
    for (int i = 0; i < 4; ++i) {
      const int mb = m0 + wr + i * 16 + lg * 4;
#pragma unroll
      for (int r = 0; r < 4; ++r) {
        const int m = mb + r;
        const int b = m >> log2R;
        const int t = m & Rmask;
        const long off = (long)b * sb + (long)t * st + (long)h * sh + (long)d * sd;
        const float v = (acc[i][j][r] + bj) * scale;
        if (OUT_BF16) ((unsigned short*)out)[off] = f2bf(v);
        else          ((float*)out)[off] = v;
      }
    }
  }
}

struct GemmDesc {
  const unsigned short* A;
  const unsigned short* W;
  const float* bias;
  unsigned short* out;
  float scale;
  int log2R;
  int nbx;
  long sb, st, sh, sd;
};

// fused Q/K/V projections: blockIdx.z selects the descriptor
__global__ __launch_bounds__(256) void gemm_qkv(GemmDesc d0, GemmDesc d1, GemmDesc d2) {
  const GemmDesc& d = (blockIdx.z == 0) ? d0 : (blockIdx.z == 1) ? d1 : d2;
  if ((int)blockIdx.x >= d.nbx) return;
  gemm_core<true>(d.A, d.W, d.bias, d.out, d.scale, d.log2R,
                  d.sb, d.st, d.sh, d.sd, blockIdx.x, blockIdx.y);
}

// output projection (fp32 out)
__global__ __launch_bounds__(256) void gemm_o(
    const unsigned short* __restrict__ A,
    const unsigned short* __restrict__ W,
    const float* __restrict__ bias,
    float* __restrict__ out,
    long sb, long st, long sh, long sd)
{
  gemm_core<false>(A, W, bias, out, 1.0f, 10, sb, st, sh, sd, blockIdx.x, blockIdx.y);
}

// ---------------- fused flash attention with additive bias ----------------
// Qb: [B*H, T, 64] bf16 (pre-scaled by 1/8); Kb: [B*H, S, 64]; Vt: [B*H, 64, S] (transposed)
// bias fp32 [B*H,T,S]; Ob: [B*H, T, 64] bf16
__global__ __launch_bounds__(256) void attn_fused(
    const unsigned short* __restrict__ Qb,
    const unsigned short* __restrict__ Kb,
    const unsigned short* __restrict__ Vt,
    const float* __restrict__ bias,
    unsigned short* __restrict__ Ob)
{
  constexpr int T = 1024, S = 2048;
  __shared__ unsigned short Ks[64 * 72];      // [s][d] +8 pad
  __shared__ unsigned short Vs[64 * 72];      // [d][s] +8 pad
  __shared__ unsigned short Ps[4][32 * 72];   // per-wave P tile [t][s]

  const int tid = threadIdx.x;
  const int w = tid >> 6, lane = tid & 63;
  const int lg = lane >> 4, ll = lane & 15;
  const int t0 = blockIdx.x * 128;
  const int bh = blockIdx.z * 16 + blockIdx.y;

  bf16x8 qf[2][2];
#pragma unroll
  for (int rf = 0; rf < 2; ++rf)
#pragma unroll
    for (int ks = 0; ks < 2; ++ks)
      qf[rf][ks] = *(const bf16x8*)(Qb + ((long)bh * T + t0 + w * 32 + rf * 16 + ll) * 64 + ks * 32 + lg * 8);

  f32x4 acc[2][4] = {};
  f32x4 m_run[2], l_run[2];
#pragma unroll
  for (int rf = 0; rf < 2; ++rf)
#pragma unroll
    for (int r = 0; r < 4; ++r) { m_run[rf][r] = -1e30f; l_run[rf][r] = 0.0f; }

  const char* Kg = (const char*)(Kb + (long)bh * S * 64);
  const char* Vg = (const char*)(Vt + (long)bh * 64 * S);
  const float* biasg = bias + ((long)bh * T + t0) * S;

  // T14 async-STAGE split: registers for the in-flight K/V chunk
  const int o0   = tid * 16;
  const int row0 = o0 >> 7, colb0 = o0 & 127;
  const int o1   = (tid + 256) * 16;
  const int row1 = o1 >> 7, colb1 = o1 & 127;

  uint4 kreg[2], vreg[2];
  auto load_chunk = [&](int sc) {
    kreg[0] = *(const uint4*)(Kg + (long)(sc * 64 + row0) * 128 + colb0);
    vreg[0] = *(const uint4*)(Vg + (long)row0 * (S * 2) + sc * 128 + colb0);
    kreg[1] = *(const uint4*)(Kg + (long)(sc * 64 + row1) * 128 + colb1);
    vreg[1] = *(const uint4*)(Vg + (long)row1 * (S * 2) + sc * 128 + colb1);
  };
  load_chunk(0);

  for (int sc = 0; sc < S / 64; ++sc) {
    // write staged regs -> padded LDS
    *(uint4*)((char*)&Ks[0] + row0 * 144 + colb0) = kreg[0];
    *(uint4*)((char*)&Vs[0] + row0 * 144 + colb0) = vreg[0];
    *(uint4*)((char*)&Ks[0] + row1 * 144 + colb1) = kreg[1];
    *(uint4*)((char*)&Vs[0] + row1 * 144 + colb1) = vreg[1];
    __syncthreads();

    // issue next chunk's global loads now; latency hides under compute below
    if (sc + 1 < S / 64) load_chunk(sc + 1);

    // QK^T for this wave's 32 rows x 64 cols
    f32x4 sv[2][4] = {};
#pragma unroll
    for (int ks = 0; ks < 2; ++ks) {
      bf16x8 kf[4];
#pragma unroll
      for (int sf = 0; sf < 4; ++sf)
        kf[sf] = *(const bf16x8*)((const char*)&Ks[0] + (sf * 16 + ll) * 144 + (ks * 32 + lg * 8) * 2);
#pragma unroll
      for (int rf = 0; rf < 2; ++rf)
#pragma unroll
        for (int sf = 0; sf < 4; ++sf)
          sv[rf][sf] = __builtin_amdgcn_mfma_f32_16x16x32_bf16(qf[rf][ks], kf[sf], sv[rf][sf], 0, 0, 0);
    }

    // bias add + online softmax
#pragma unroll
    for (int rf = 0; rf < 2; ++rf) {
      const int trow = w * 32 + rf * 16 + lg * 4;
#pragma unroll
      for (int sf = 0; sf < 4; ++sf) {
        const long bo_ = (long)trow * S + sc * 64 + sf * 16 + ll;
#pragma unroll
        for (int r = 0; r < 4; ++r)
          sv[rf][sf][r] += biasg[bo_ + (long)r * S];
      }
      f32x4 rmax;
#pragma unroll
      for (int r = 0; r < 4; ++r)
        rmax[r] = fmaxf(fmaxf(sv[rf][0][r], sv[rf][1][r]), fmaxf(sv[rf][2][r], sv[rf][3][r]));
#pragma unroll
      for (int off = 1; off < 16; off <<= 1)
#pragma unroll
        for (int r = 0; r < 4; ++r)
          rmax[r] = fmaxf(rmax[r], __shfl_xor(rmax[r], off));
      f32x4 mnew, alpha, rsum;
#pragma unroll
      for (int r = 0; r < 4; ++r) {
        mnew[r]  = fmaxf(m_run[rf][r], rmax[r]);
        alpha[r] = __expf(m_run[rf][r] - mnew[r]);
        rsum[r]  = 0.0f;
      }
#pragma unroll
      for (int sf = 0; sf < 4; ++sf)
#pragma unroll
        for (int r = 0; r < 4; ++r) {
          const float p = __expf(sv[rf][sf][r] - mnew[r]);
          sv[rf][sf][r] = p;
          rsum[r] += p;
        }
#pragma unroll
      for (int off = 1; off < 16; off <<= 1)
#pragma unroll
        for (int r = 0; r < 4; ++r)
          rsum[r] += __shfl_xor(rsum[r], off);
#pragma unroll
      for (int r = 0; r < 4; ++r) {
        l_run[rf][r] = l_run[rf][r] * alpha[r] + rsum[r];
        m_run[rf][r] = mnew[r];
      }
#pragma unroll
      for (int df = 0; df < 4; ++df)
#pragma unroll
        for (int r = 0; r < 4; ++r)
          acc[rf][df][r] *= alpha[r];
      // write P (bf16) into this wave's private LDS tile
      unsigned short* Pw = &Ps[w][0];
#pragma unroll
      for (int sf = 0; sf < 4; ++sf)
#pragma unroll
        for (int r = 0; r < 4; ++r)
          Pw[(rf * 16 + lg * 4 + r) * 72 + sf * 16 + ll] = f2bf(sv[rf][sf][r]);
    }

    // intra-wave LDS write->read ordering (private tile, no barrier needed)
    asm volatile("s_waitcnt lgkmcnt(0)" ::: "memory");

    // PV: acc[t][d] += P[t][s] * V[s][d]
#pragma unroll
    for (int ks = 0; ks < 2; ++ks) {
      bf16x8 pa[2], vf[4];
#pragma unroll
      for (int rf = 0; rf < 2; ++rf)
        pa[rf] = *(const bf16x8*)((const char*)&Ps[w][0] + (rf * 16 + ll) * 144 + (ks * 32 + lg * 8) * 2);
#pragma unroll
      for (int df = 0; df < 4; ++df)
        vf[df] = *(const bf16x8*)((const char*)&Vs[0] + (df * 16 + ll) * 144 + (ks * 32 + lg * 8) * 2);
#pragma unroll
      for (int rf = 0; rf < 2; ++rf)
#pragma unroll
        for (int df = 0; df < 4; ++df)
          acc[rf][df] = __builtin_amdgcn_mfma_f32_16x16x32_bf16(pa[rf], vf[df], acc[rf][df], 0, 0, 0);
    }
    __syncthreads();
  }

  // epilogue: normalize by l and store bf16 [B*H, T, 64]
#pragma unroll
  for (int rf = 0; rf < 2; ++rf) {
    f32x4 inv;
#pragma unroll
    for (int r = 0; r < 4; ++r) inv[r] = 1.0f / l_run[rf][r];
#pragma unroll
    for (int df = 0; df < 4; ++df)
#pragma unroll
      for (int r = 0; r < 4; ++r) {
        const long oo = ((long)bh * T + t0 + w * 32 + rf * 16 + lg * 4 + r) * 64 + df * 16 + ll;
        Ob[oo] = f2bf(acc[rf][df][r] * inv[r]);
      }
  }
}

// ---------------- host launch ----------------
extern "C" void kernel_launch(void* const* d_in, const int* in_sizes, int n_in,
                              void* d_out, int out_size, void* d_ws, size_t ws_size,
                              hipStream_t stream) {
  constexpr int B = 4, T = 1024, S = 2048, E = 1024;
  const float* hs   = (const float*)d_in[0];
  const float* kv   = (const float*)d_in[1];
  const float* bias = (const float*)d_in[2];
  const float* Wq   = (const float*)d_in[3];
  const float* bq   = (const float*)d_in[4];
  const float* Wk   = (const float*)d_in[5];
  const float* bk   = (const float*)d_in[6];
  const float* Wv   = (const float*)d_in[7];
  const float* bv   = (const float*)d_in[8];
  const float* Wo   = (const float*)d_in[9];
  const float* bo   = (const float*)d_in[10];

  char* ws = (char*)d_ws;
  const size_t MB = 1024 * 1024;
  unsigned short* hs_bf = (unsigned short*)(ws);            // 8 MB
  unsigned short* kv_bf = (unsigned short*)(ws + 8 * MB);   // 16 MB
  unsigned short* wq_bf = (unsigned short*)(ws + 24 * MB);  // 2 MB
  unsigned short* wk_bf = (unsigned short*)(ws + 26 * MB);  // 2 MB
  unsigned short* wv_bf = (unsigned short*)(ws + 28 * MB);  // 2 MB
  unsigned short* wo_bf = (unsigned short*)(ws + 30 * MB);  // 2 MB
  unsigned short* q_buf = (unsigned short*)(ws + 32 * MB);  // 8 MB  [B,H,T,64]
  unsigned short* k_buf = (unsigned short*)(ws + 40 * MB);  // 16 MB [B,H,S,64]
  unsigned short* v_buf = (unsigned short*)(ws + 56 * MB);  // 16 MB [B,H,64,S]
  unsigned short* a_buf = (unsigned short*)(ws + 72 * MB);  // 8 MB  [B,H,T,64]

  // one fused conversion launch: hs, kv, Wq, Wk, Wv, Wo
  CvtArgs ca;
  ca.src[0] = hs;  ca.dst[0] = hs_bf;
  ca.src[1] = kv;  ca.dst[1] = kv_bf;
  ca.src[2] = Wq;  ca.dst[2] = wq_bf;
  ca.src[3] = Wk;  ca.dst[3] = wk_bf;
  ca.src[4] = Wv;  ca.dst[4] = wv_bf;
  ca.src[5] = Wo;  ca.dst[5] = wo_bf;
  const int n4_hs = B * T * E / 4, n4_kv = B * S * E / 4, n4_w = E * E / 4;
  ca.cum[0] = 0;
  ca.cum[1] = n4_hs;
  ca.cum[2] = n4_hs + n4_kv;
  ca.cum[3] = n4_hs + n4_kv + n4_w;
  ca.cum[4] = n4_hs + n4_kv + 2 * n4_w;
  ca.cum[5] = n4_hs + n4_kv + 3 * n4_w;
  const int total4 = n4_hs + n4_kv + 4 * n4_w;
  cvt_all<<<dim3((total4 + 255) / 256), dim3(256), 0, stream>>>(ca, total4);

  // fused Q/K/V projection launch (z selects descriptor)
  GemmDesc dq{hs_bf, wq_bf, bq, q_buf, 0.125f, 10, 32,
              (long)T * E, 64L, (long)T * 64, 1L};
  GemmDesc dk{kv_bf, wk_bf, bk, k_buf, 1.0f, 11, 64,
              (long)S * E, 64L, (long)S * 64, 1L};
  GemmDesc dv{kv_bf, wv_bf, bv, v_buf, 1.0f, 11, 64,
              (long)S * E, 1L, (long)S * 64, (long)S};
  gemm_qkv<<<dim3(64, 8, 3), 256, 0, stream>>>(dq, dk, dv);

  attn_fused<<<dim3(T / 128, 16, B), 256, 0, stream>>>(q_buf, k_buf, v_buf, bias, a_buf);

  // out = attn_flat @ Wo^T + bo  (flat [B,H,T,64] == the reference's reshape)
  gemm_o<<<dim3(32, 8), 256, 0, stream>>>(
      a_buf, wo_bf, bo, (float*)d_out,
      (long)T * E, (long)E, 64L, 1L);
}

// Round 3
// 306.144 us; speedup vs baseline: 1.1409x; 1.1409x over previous
//
#include <hip/hip_runtime.h>

#define DEVI __device__ __forceinline__

typedef __attribute__((ext_vector_type(4))) float f32x4;
typedef __attribute__((ext_vector_type(8))) short bf16x8;

DEVI unsigned short f2bf(float f) {
  unsigned int u = __builtin_bit_cast(unsigned int, f);
  u += 0x7FFFu + ((u >> 16) & 1u);   // round-to-nearest-even
  return (unsigned short)(u >> 16);
}

DEVI void load_lds16(const void* g, void* l) {
  __builtin_amdgcn_global_load_lds(
      (__attribute__((address_space(1))) void*)g,
      (__attribute__((address_space(3))) void*)l,
      16, 0, 0);
}

// ---------------- fused fp32 -> bf16 bulk convert (6 segments, 1 launch) ----------------
struct CvtArgs {
  const float* src[6];
  unsigned short* dst[6];
  int cum[6];
};

__global__ __launch_bounds__(256) void cvt_all(CvtArgs a, int total4) {
  int i = blockIdx.x * 256 + threadIdx.x;
  if (i >= total4) return;
  int s = 0;
#pragma unroll
  for (int k = 1; k < 6; ++k) s += (i >= a.cum[k]);
  const int j = i - a.cum[s];
  const float4 v = reinterpret_cast<const float4*>(a.src[s])[j];
  ushort4 o;
  o.x = f2bf(v.x); o.y = f2bf(v.y); o.z = f2bf(v.z); o.w = f2bf(v.w);
  reinterpret_cast<ushort4*>(a.dst[s])[j] = o;
}

// ---------------- shared 128x128xK=1024 GEMM core ----------------
// C = A @ W^T + bias. A: [M,1024] bf16; W: [1024,1024] bf16 (row-major, = W^T access).
// Normal epilogue: out (m,n): b=m>>log2R, t=m&mask, h=n>>6, d=n&63,
//                  off=b*sb+t*st+h*sh+d*sd.
// vt epilogue (V projection): out[b][h][d][t] with coalesced t-runs via LDS transpose.
template<bool OUT_BF16>
DEVI void gemm_core(const unsigned short* __restrict__ A,
                    const unsigned short* __restrict__ W,
                    const float* __restrict__ bias,
                    void* __restrict__ out,
                    float scale, int log2R,
                    long sb, long st, long sh, long sd,
                    int bx, int by, bool vt)
{
  constexpr int K = 1024;
  __shared__ unsigned short smem[2 * 128 * 64];   // As = smem, Bs = smem + 8192
  unsigned short* As = smem;
  unsigned short* Bs = smem + 8192;

  const int tid  = threadIdx.x;
  const int wid  = tid >> 6;
  const int lane = tid & 63;
  const int m0 = bx * 128;
  const int n0 = by * 128;
  const int wr = (wid >> 1) * 64;
  const int wc = (wid & 1) * 64;
  const int lg = lane >> 4;
  const int ll = lane & 15;

  f32x4 acc[4][4] = {};

  const char* Ab = (const char*)A + (long)m0 * K * 2;
  const char* Wb = (const char*)W + (long)n0 * K * 2;
  char* AsB = (char*)As;
  char* BsB = (char*)Bs;
  const long rowstride = (long)K * 2;

  for (int kt = 0; kt < K; kt += 64) {
#pragma unroll
    for (int j = 0; j < 4; ++j) {
      const int o    = (wid * 4 + j) * 1024 + lane * 16;
      const int row  = o >> 7;
      const int colb = o & 127;
      load_lds16(Ab + (long)row * rowstride + (long)kt * 2 + colb, AsB + (wid * 4 + j) * 1024);
      load_lds16(Wb + (long)row * rowstride + (long)kt * 2 + colb, BsB + (wid * 4 + j) * 1024);
    }
    __syncthreads();
#pragma unroll
    for (int ks = 0; ks < 2; ++ks) {
      bf16x8 af[4], bfr[4];
#pragma unroll
      for (int i = 0; i < 4; ++i) {
        af[i]  = *(const bf16x8*)&As[(wr + i * 16 + ll) * 64 + ks * 32 + lg * 8];
        bfr[i] = *(const bf16x8*)&Bs[(wc + i * 16 + ll) * 64 + ks * 32 + lg * 8];
      }
#pragma unroll
      for (int i = 0; i < 4; ++i)
#pragma unroll
        for (int j = 0; j < 4; ++j)
          acc[i][j] = __builtin_amdgcn_mfma_f32_16x16x32_bf16(af[i], bfr[j], acc[i][j], 0, 0, 0);
    }
    __syncthreads();
  }

  if (OUT_BF16 && vt) {
    // ---- V epilogue: per-wave LDS transpose -> coalesced t-runs ----
    // out off = b*sb + h*sh + d*sd + t*st  (st=1, sd=S)
    const int m_base = m0 + wr;                       // tile's t-start (b constant: 128-tile within 2^log2R rows)
    const int b  = m_base >> log2R;
    const int tb = m_base & ((1 << log2R) - 1);
    unsigned short* Tw = smem + wid * 2176;           // 32 rows x 68 pad (4352 B/wave, fits in As region)
#pragma unroll
    for (int h2 = 0; h2 < 2; ++h2) {
#pragma unroll
      for (int jj = 0; jj < 2; ++jj) {
        const int j = h2 * 2 + jj;
        const float bj = bias[n0 + wc + j * 16 + ll];
#pragma unroll
        for (int i = 0; i < 4; ++i)
#pragma unroll
          for (int r = 0; r < 4; ++r)
            Tw[(jj * 16 + ll) * 68 + i * 16 + lg * 4 + r] = f2bf((acc[i][j][r] + bj) * scale);
      }
      asm volatile("s_waitcnt lgkmcnt(0)" ::: "memory");
#pragma unroll
      for (int k = 0; k < 8; ++k) {
        const int dloc = k * 4 + (lane >> 4);
        const int t4   = (lane & 15) * 4;
        const ushort4 vv = *(const ushort4*)&Tw[dloc * 68 + t4];
        const int n = n0 + wc + h2 * 32 + dloc;
        const int h = n >> 6, dd = n & 63;
        *(ushort4*)((unsigned short*)out + (long)b * sb + (long)h * sh + (long)dd * sd + tb + t4) = vv;
      }
      if (h2 == 0) asm volatile("s_waitcnt lgkmcnt(0)" ::: "memory");
    }
    return;
  }

  const int Rmask = (1 << log2R) - 1;
#pragma unroll
  for (int j = 0; j < 4; ++j) {
    const int n = n0 + wc + j * 16 + ll;
    const float bj = bias[n];
    const int h = n >> 6, d = n & 63;
#pragma unroll
    for (int i = 0; i < 4; ++i) {
      const int mb = m0 + wr + i * 16 + lg * 4;
#pragma unroll
      for (int r = 0; r < 4; ++r) {
        const int m = mb + r;
        const int b = m >> log2R;
        const int t = m & Rmask;
        const long off = (long)b * sb + (long)t * st + (long)h * sh + (long)d * sd;
        const float v = (acc[i][j][r] + bj) * scale;
        if (OUT_BF16) ((unsigned short*)out)[off] = f2bf(v);
        else          ((float*)out)[off] = v;
      }
    }
  }
}

struct GemmDesc {
  const unsigned short* A;
  const unsigned short* W;
  const float* bias;
  unsigned short* out;
  float scale;
  int log2R;
  long sb, st, sh, sd;
};

// fused Q/K/V projections: flat 1-D grid, no dead blocks
// blocks: [0,256) Q (32x8), [256,768) K (64x8), [768,1280) V (64x8, transposed epilogue)
__global__ __launch_bounds__(256) void gemm_qkv(GemmDesc d0, GemmDesc d1, GemmDesc d2) {
  int bid = blockIdx.x;
  const GemmDesc* d;
  bool vt = false;
  if (bid < 256)      { d = &d0; }
  else if (bid < 768) { d = &d1; bid -= 256; }
  else                { d = &d2; bid -= 768; vt = true; }
  gemm_core<true>(d->A, d->W, d->bias, d->out, d->scale, d->log2R,
                  d->sb, d->st, d->sh, d->sd, bid >> 3, bid & 7, vt);
}

// output projection (fp32 out)
__global__ __launch_bounds__(256) void gemm_o(
    const unsigned short* __restrict__ A,
    const unsigned short* __restrict__ W,
    const float* __restrict__ bias,
    float* __restrict__ out,
    long sb, long st, long sh, long sd)
{
  gemm_core<false>(A, W, bias, out, 1.0f, 10, sb, st, sh, sd, blockIdx.x, blockIdx.y, false);
}

// ---------------- fused flash attention with additive bias ----------------
// Qb: [B*H, T, 64] bf16 (pre-scaled by 1/8); Kb: [B*H, S, 64]; Vt: [B*H, 64, S]
// bias fp32 [B*H,T,S]; Ob: [B*H, T, 64] bf16
__global__ __launch_bounds__(256) void attn_fused(
    const unsigned short* __restrict__ Qb,
    const unsigned short* __restrict__ Kb,
    const unsigned short* __restrict__ Vt,
    const float* __restrict__ bias,
    unsigned short* __restrict__ Ob)
{
  constexpr int T = 1024, S = 2048;
  __shared__ unsigned short Ks[64 * 72];
  __shared__ unsigned short Vs[64 * 72];
  __shared__ unsigned short Ps[4][32 * 72];

  const int tid = threadIdx.x;
  const int w = tid >> 6, lane = tid & 63;
  const int lg = lane >> 4, ll = lane & 15;
  const int t0 = blockIdx.x * 128;
  const int bh = blockIdx.z * 16 + blockIdx.y;

  bf16x8 qf[2][2];
#pragma unroll
  for (int rf = 0; rf < 2; ++rf)
#pragma unroll
    for (int ks = 0; ks < 2; ++ks)
      qf[rf][ks] = *(const bf16x8*)(Qb + ((long)bh * T + t0 + w * 32 + rf * 16 + ll) * 64 + ks * 32 + lg * 8);

  f32x4 acc[2][4] = {};
  f32x4 m_run[2], l_run[2];
#pragma unroll
  for (int rf = 0; rf < 2; ++rf)
#pragma unroll
    for (int r = 0; r < 4; ++r) { m_run[rf][r] = -1e30f; l_run[rf][r] = 0.0f; }

  const char* Kg = (const char*)(Kb + (long)bh * S * 64);
  const char* Vg = (const char*)(Vt + (long)bh * 64 * S);
  const float* biasg = bias + ((long)bh * T + t0) * S;

  for (int sc = 0; sc < S / 64; ++sc) {
    // stage K chunk [64 s][64 d] and V^T chunk [64 d][64 s] into padded LDS
#pragma unroll
    for (int r2 = 0; r2 < 2; ++r2) {
      const int o = (tid + r2 * 256) * 16;
      const int row = o >> 7, colb = o & 127;
      uint4 kd = *(const uint4*)(Kg + (long)(sc * 64 + row) * 128 + colb);
      *(uint4*)((char*)&Ks[0] + row * 144 + colb) = kd;
      uint4 vd = *(const uint4*)(Vg + (long)row * (S * 2) + sc * 128 + colb);
      *(uint4*)((char*)&Vs[0] + row * 144 + colb) = vd;
    }
    __syncthreads();

    // QK^T
    f32x4 sv[2][4] = {};
#pragma unroll
    for (int ks = 0; ks < 2; ++ks) {
      bf16x8 kf[4];
#pragma unroll
      for (int sf = 0; sf < 4; ++sf)
        kf[sf] = *(const bf16x8*)((const char*)&Ks[0] + (sf * 16 + ll) * 144 + (ks * 32 + lg * 8) * 2);
#pragma unroll
      for (int rf = 0; rf < 2; ++rf)
#pragma unroll
        for (int sf = 0; sf < 4; ++sf)
          sv[rf][sf] = __builtin_amdgcn_mfma_f32_16x16x32_bf16(qf[rf][ks], kf[sf], sv[rf][sf], 0, 0, 0);
    }

    // bias add + online softmax
#pragma unroll
    for (int rf = 0; rf < 2; ++rf) {
      const int trow = w * 32 + rf * 16 + lg * 4;
#pragma unroll
      for (int sf = 0; sf < 4; ++sf) {
        const long bo_ = (long)trow * S + sc * 64 + sf * 16 + ll;
#pragma unroll
        for (int r = 0; r < 4; ++r)
          sv[rf][sf][r] += biasg[bo_ + (long)r * S];
      }
      f32x4 rmax;
#pragma unroll
      for (int r = 0; r < 4; ++r)
        rmax[r] = fmaxf(fmaxf(sv[rf][0][r], sv[rf][1][r]), fmaxf(sv[rf][2][r], sv[rf][3][r]));
#pragma unroll
      for (int off = 1; off < 16; off <<= 1)
#pragma unroll
        for (int r = 0; r < 4; ++r)
          rmax[r] = fmaxf(rmax[r], __shfl_xor(rmax[r], off));
      f32x4 mnew, alpha, rsum;
#pragma unroll
      for (int r = 0; r < 4; ++r) {
        mnew[r]  = fmaxf(m_run[rf][r], rmax[r]);
        alpha[r] = __expf(m_run[rf][r] - mnew[r]);
        rsum[r]  = 0.0f;
      }
#pragma unroll
      for (int sf = 0; sf < 4; ++sf)
#pragma unroll
        for (int r = 0; r < 4; ++r) {
          const float p = __expf(sv[rf][sf][r] - mnew[r]);
          sv[rf][sf][r] = p;
          rsum[r] += p;
        }
#pragma unroll
      for (int off = 1; off < 16; off <<= 1)
#pragma unroll
        for (int r = 0; r < 4; ++r)
          rsum[r] += __shfl_xor(rsum[r], off);
#pragma unroll
      for (int r = 0; r < 4; ++r) {
        l_run[rf][r] = l_run[rf][r] * alpha[r] + rsum[r];
        m_run[rf][r] = mnew[r];
      }
#pragma unroll
      for (int df = 0; df < 4; ++df)
#pragma unroll
        for (int r = 0; r < 4; ++r)
          acc[rf][df][r] *= alpha[r];
      unsigned short* Pw = &Ps[w][0];
#pragma unroll
      for (int sf = 0; sf < 4; ++sf)
#pragma unroll
        for (int r = 0; r < 4; ++r)
          Pw[(rf * 16 + lg * 4 + r) * 72 + sf * 16 + ll] = f2bf(sv[rf][sf][r]);
    }

    asm volatile("s_waitcnt lgkmcnt(0)" ::: "memory");

    // PV
#pragma unroll
    for (int ks = 0; ks < 2; ++ks) {
      bf16x8 pa[2], vf[4];
#pragma unroll
      for (int rf = 0; rf < 2; ++rf)
        pa[rf] = *(const bf16x8*)((const char*)&Ps[w][0] + (rf * 16 + ll) * 144 + (ks * 32 + lg * 8) * 2);
#pragma unroll
      for (int df = 0; df < 4; ++df)
        vf[df] = *(const bf16x8*)((const char*)&Vs[0] + (df * 16 + ll) * 144 + (ks * 32 + lg * 8) * 2);
#pragma unroll
      for (int rf = 0; rf < 2; ++rf)
#pragma unroll
        for (int df = 0; df < 4; ++df)
          acc[rf][df] = __builtin_amdgcn_mfma_f32_16x16x32_bf16(pa[rf], vf[df], acc[rf][df], 0, 0, 0);
    }
    __syncthreads();
  }

#pragma unroll
  for (int rf = 0; rf < 2; ++rf) {
    f32x4 inv;
#pragma unroll
    for (int r = 0; r < 4; ++r) inv[r] = 1.0f / l_run[rf][r];
#pragma unroll
    for (int df = 0; df < 4; ++df)
#pragma unroll
      for (int r = 0; r < 4; ++r) {
        const long oo = ((long)bh * T + t0 + w * 32 + rf * 16 + lg * 4 + r) * 64 + df * 16 + ll;
        Ob[oo] = f2bf(acc[rf][df][r] * inv[r]);
      }
  }
}

// ---------------- host launch ----------------
extern "C" void kernel_launch(void* const* d_in, const int* in_sizes, int n_in,
                              void* d_out, int out_size, void* d_ws, size_t ws_size,
                              hipStream_t stream) {
  constexpr int B = 4, T = 1024, S = 2048, E = 1024;
  const float* hs   = (const float*)d_in[0];
  const float* kv   = (const float*)d_in[1];
  const float* bias = (const float*)d_in[2];
  const float* Wq   = (const float*)d_in[3];
  const float* bq   = (const float*)d_in[4];
  const float* Wk   = (const float*)d_in[5];
  const float* bk   = (const float*)d_in[6];
  const float* Wv   = (const float*)d_in[7];
  const float* bv   = (const float*)d_in[8];
  const float* Wo   = (const float*)d_in[9];
  const float* bo   = (const float*)d_in[10];

  char* ws = (char*)d_ws;
  const size_t MB = 1024 * 1024;
  unsigned short* hs_bf = (unsigned short*)(ws);            // 8 MB
  unsigned short* kv_bf = (unsigned short*)(ws + 8 * MB);   // 16 MB
  unsigned short* wq_bf = (unsigned short*)(ws + 24 * MB);  // 2 MB
  unsigned short* wk_bf = (unsigned short*)(ws + 26 * MB);  // 2 MB
  unsigned short* wv_bf = (unsigned short*)(ws + 28 * MB);  // 2 MB
  unsigned short* wo_bf = (unsigned short*)(ws + 30 * MB);  // 2 MB
  unsigned short* q_buf = (unsigned short*)(ws + 32 * MB);  // 8 MB  [B,H,T,64]
  unsigned short* k_buf = (unsigned short*)(ws + 40 * MB);  // 16 MB [B,H,S,64]
  unsigned short* v_buf = (unsigned short*)(ws + 56 * MB);  // 16 MB [B,H,64,S]
  unsigned short* a_buf = (unsigned short*)(ws + 72 * MB);  // 8 MB  [B,H,T,64]

  CvtArgs ca;
  ca.src[0] = hs;  ca.dst[0] = hs_bf;
  ca.src[1] = kv;  ca.dst[1] = kv_bf;
  ca.src[2] = Wq;  ca.dst[2] = wq_bf;
  ca.src[3] = Wk;  ca.dst[3] = wk_bf;
  ca.src[4] = Wv;  ca.dst[4] = wv_bf;
  ca.src[5] = Wo;  ca.dst[5] = wo_bf;
  const int n4_hs = B * T * E / 4, n4_kv = B * S * E / 4, n4_w = E * E / 4;
  ca.cum[0] = 0;
  ca.cum[1] = n4_hs;
  ca.cum[2] = n4_hs + n4_kv;
  ca.cum[3] = n4_hs + n4_kv + n4_w;
  ca.cum[4] = n4_hs + n4_kv + 2 * n4_w;
  ca.cum[5] = n4_hs + n4_kv + 3 * n4_w;
  const int total4 = n4_hs + n4_kv + 4 * n4_w;
  cvt_all<<<dim3((total4 + 255) / 256), dim3(256), 0, stream>>>(ca, total4);

  GemmDesc dq{hs_bf, wq_bf, bq, q_buf, 0.125f, 10,
              (long)T * E, 64L, (long)T * 64, 1L};
  GemmDesc dk{kv_bf, wk_bf, bk, k_buf, 1.0f, 11,
              (long)S * E, 64L, (long)S * 64, 1L};
  GemmDesc dv{kv_bf, wv_bf, bv, v_buf, 1.0f, 11,
              (long)S * E, 1L, (long)S * 64, (long)S};
  gemm_qkv<<<dim3(1280), 256, 0, stream>>>(dq, dk, dv);

  attn_fused<<<dim3(T / 128, 16, B), 256, 0, stream>>>(q_buf, k_buf, v_buf, bias, a_buf);

  gemm_o<<<dim3(32, 8), 256, 0, stream>>>(
      a_buf, wo_bf, bo, (float*)d_out,
      (long)T * E, (long)E, 64L, 1L);
}